// Round 4
// baseline (3663.697 us; speedup 1.0000x reference)
//
#include <hip/hip_runtime.h>
#include <stdint.h>

#define MDIM 512
#define NDIM 512
#define NTHREADS 512

typedef unsigned long long u64;

// max-reduce a packed (value, inverted-index) u64 across the 64-lane wave
__device__ __forceinline__ u64 wave_max_u64(u64 v) {
#pragma unroll
  for (int off = 32; off; off >>= 1) {
    u64 q = __shfl_xor(v, off);
    if (q > v) v = q;
  }
  return v;
}

// One block per batch element. Greedy MCS tree search with incremental
// frontier / per-row-max maintenance. Tie-breaking matches jnp.argmax
// (first maximum in row-major flat order) via packed u64 compares.
__global__ __launch_bounds__(NTHREADS, 1) void tree_search_kernel(
    const float* __restrict__ y,
    const float* __restrict__ a1,
    const float* __restrict__ a2,
    float* __restrict__ out)
{
  const int b   = blockIdx.x;
  const int tid = threadIdx.x;
  const float* __restrict__ Y  = y  + (size_t)b * (MDIM * NDIM);
  const float* __restrict__ A1 = a1 + (size_t)b * (MDIM * MDIM);
  const float* __restrict__ A2 = a2 + (size_t)b * (NDIM * NDIM);
  float* __restrict__ O = out + (size_t)b * (MDIM * NDIM);

  // row: 0 = never reached, 1 = active (in F1), 2 = pending recompute, 3 = selected
  __shared__ unsigned rowState[MDIM];
  __shared__ float    rowMax[MDIM];    // best y over current F2, per active row
  __shared__ unsigned rowArg[MDIM];    // argmax col (smallest col on ties)
  // col: 0 = never reached, 1 = in F2, 2 = selected
  __shared__ unsigned colState[NDIM];
  __shared__ unsigned colList[NDIM];   // compressed F2 (unordered)
  __shared__ unsigned colPos[NDIM];    // position of col in colList
  __shared__ unsigned newCols[NDIM];   // cols added this iteration
  __shared__ unsigned addRows[MDIM];   // rows needing from-scratch recompute
  __shared__ int s_colCount, s_nAdd, s_nNew, s_stop, s_ci, s_cj;
  __shared__ u64 s_part[NTHREADS / 64];

  rowState[tid] = 0u;
  colState[tid] = 0u;
  rowMax[tid]   = 0.f;
  rowArg[tid]   = 511u;
  if (tid == 0) { s_colCount = 0; s_nAdd = 0; s_nNew = 0; s_stop = 0; }
  __syncthreads();

  // ---------- iteration 0: fmask == ones -> global argmax over all of Y ----------
  {
    u64 best = 0;
    for (int base = tid * 4; base < MDIM * NDIM; base += NTHREADS * 4) {
      const float4 v = *reinterpret_cast<const float4*>(Y + base);
      const float vv[4] = {v.x, v.y, v.z, v.w};
#pragma unroll
      for (int c = 0; c < 4; ++c) {
        u64 p = ((u64)__float_as_uint(vv[c]) << 32)
                | (u64)(262143u - (unsigned)(base + c));
        if (p > best) best = p;
      }
    }
    best = wave_max_u64(best);
    if ((tid & 63) == 0) s_part[tid >> 6] = best;
    __syncthreads();
    if (tid == 0) {
      u64 bst = s_part[0];
#pragma unroll
      for (int w = 1; w < NTHREADS / 64; ++w) if (s_part[w] > bst) bst = s_part[w];
      float v = __uint_as_float((unsigned)(bst >> 32));
      if (v >= 0.5f) {
        unsigned key = 262143u - (unsigned)(bst & 0xFFFFFFFFu);
        int bi = key >> 9, bj = key & 511;
        rowState[bi] = 3u;
        colState[bj] = 2u;
        O[key] = 1.0f;
        s_ci = bi; s_cj = bj;
      } else {
        s_stop = 1;
      }
    }
    __syncthreads();
  }

  // ---------- main loop ----------
  while (!s_stop) {
    // Phase A: expand frontiers from the committed (ci, cj).
    // Each thread owns exactly one row index and one col index (== tid).
    {
      const int r = tid;
      const unsigned st = rowState[r];
      const float av = A1[(size_t)s_ci * MDIM + r];
      const bool newRow   = (av != 0.f) && (st == 0u);
      const bool recompute = (st == 1u) && (rowArg[r] == (unsigned)s_cj);
      if (newRow || recompute) {
        rowState[r] = 2u;                       // pending
        addRows[atomicAdd(&s_nAdd, 1)] = (unsigned)r;
      }
      const float bv = A2[(size_t)s_cj * NDIM + r];
      if (bv != 0.f && colState[r] == 0u) {
        colState[r] = 1u;
        newCols[atomicAdd(&s_nNew, 1)] = (unsigned)r;
        int p = atomicAdd(&s_colCount, 1);
        colList[p] = (unsigned)r;
        colPos[r]  = (unsigned)p;
      }
    }
    __syncthreads();

    // Phase B1: active rows fold in the newly-added columns (incremental).
    {
      const int r = tid;
      if (rowState[r] == 1u) {
        float rm = rowMax[r];
        unsigned ra = rowArg[r];
        const int nn = s_nNew;
        for (int k = 0; k < nn; ++k) {
          const unsigned c = newCols[k];         // LDS broadcast
          const float v = Y[((unsigned)r << 9) + c];
          if (v > rm || (v == rm && c < ra)) { rm = v; ra = c; }
        }
        rowMax[r] = rm; rowArg[r] = ra;
      }
    }
    // Barrier: B2 writes rowState/rowMax/rowArg for pending rows; without this
    // fence a fast wave's B2 update could interleave with another wave's B1
    // read-modify-write of the same row (LDS write order across waves is not
    // guaranteed) and clobber a correct recompute with a stale partial max.
    __syncthreads();

    // Phase B2: pending rows recompute from scratch over the full F2 list.
    // 8 lanes per row, 64 rows in flight. Disjoint from B1's row set.
    {
      const int g = tid >> 3, lane = tid & 7;
      const int nAdd = s_nAdd, cc = s_colCount;
      for (int a = g; a < nAdd; a += NTHREADS / 8) {
        const int rr = (int)addRows[a];
        float rm = 0.f;
        unsigned ra = 511u;
        for (int k = lane; k < cc; k += 8) {
          const unsigned c = colList[k];
          const float v = Y[((unsigned)rr << 9) + c];
          if (v > rm || (v == rm && c < ra)) { rm = v; ra = c; }
        }
        u64 p = ((u64)__float_as_uint(rm) << 32) | (u64)(511u - ra);
#pragma unroll
        for (int off = 4; off; off >>= 1) {
          u64 q = __shfl_xor(p, off, 8);
          if (q > p) p = q;
        }
        if (lane == 0) {
          rowMax[rr]   = __uint_as_float((unsigned)(p >> 32));
          rowArg[rr]   = 511u - (unsigned)(p & 0xFFFFFFFFu);
          rowState[rr] = 1u;
        }
      }
    }
    __syncthreads();

    // Phase C: global argmax over active rows (value desc, flat index asc).
    {
      u64 cand = 0;
      if (rowState[tid] == 1u) {
        const unsigned key = ((unsigned)tid << 9) | rowArg[tid];
        cand = ((u64)__float_as_uint(rowMax[tid]) << 32)
               | (u64)(262143u - key);
      }
      cand = wave_max_u64(cand);
      if ((tid & 63) == 0) s_part[tid >> 6] = cand;
    }
    __syncthreads();

    // Commit (single thread): threshold check BEFORE commit, like the reference.
    if (tid == 0) {
      u64 bst = s_part[0];
#pragma unroll
      for (int w = 1; w < NTHREADS / 64; ++w) if (s_part[w] > bst) bst = s_part[w];
      const float v = __uint_as_float((unsigned)(bst >> 32));
      if (v >= 0.5f) {
        const unsigned key = 262143u - (unsigned)(bst & 0xFFFFFFFFu);
        const int bi = key >> 9, bj = key & 511;
        rowState[bi] = 3u;
        colState[bj] = 2u;
        // swap-remove bj from the compressed F2 list
        const int p    = (int)colPos[bj];
        const int last = (int)colList[s_colCount - 1];
        colList[p]    = (unsigned)last;
        colPos[last]  = (unsigned)p;
        s_colCount--;
        O[key] = 1.0f;
        s_ci = bi; s_cj = bj;
        s_nAdd = 0; s_nNew = 0;
      } else {
        s_stop = 1;
      }
    }
    __syncthreads();
  }
}

extern "C" void kernel_launch(void* const* d_in, const int* in_sizes, int n_in,
                              void* d_out, int out_size, void* d_ws, size_t ws_size,
                              hipStream_t stream) {
  const float* y  = (const float*)d_in[0];
  const float* a1 = (const float*)d_in[1];
  const float* a2 = (const float*)d_in[2];
  float* out = (float*)d_out;
  const int B = in_sizes[0] / (MDIM * NDIM);

  // d_out is poisoned with 0xAA before every launch -> zero it first.
  (void)hipMemsetAsync(d_out, 0, (size_t)out_size * sizeof(float), stream);
  tree_search_kernel<<<B, NTHREADS, 0, stream>>>(y, a1, a2, out);
}